// Round 1
// baseline (412.824 us; speedup 1.0000x reference)
//
#include <hip/hip_runtime.h>
#include <hip/hip_bf16.h>
#include <cstddef>

// Problem constants (from setup_inputs): B=16, n=4096, m=1024, C1=128, C2=C=256
#define BATCH 16
#define NPTS  4096
#define MPTS  1024
#define PTOT  65536      // BATCH*NPTS
#define C1    128
#define C2    256

typedef short bf16x8 __attribute__((ext_vector_type(8)));
typedef float f32x4  __attribute__((ext_vector_type(4)));

static __device__ __forceinline__ float bf2f(unsigned int u16) {
    union { unsigned int i; float f; } v; v.i = u16 << 16; return v.f;
}
static __device__ __forceinline__ unsigned short f2bf(float f) {
    union { float f; unsigned int i; } v; v.f = f;
    unsigned int u = v.i;
    return (unsigned short)((u + 0x7FFFu + ((u >> 16) & 1u)) >> 16);
}

// ---------------------------------------------------------------------------
// Transpose (B, C, N) f32  ->  (B, N, C) bf16
// ---------------------------------------------------------------------------
__global__ void k_transpose(const float* __restrict__ in, unsigned short* __restrict__ out,
                            int C, int N) {
    __shared__ float tile[64][65];
    int b  = blockIdx.z;
    int n0 = blockIdx.x * 64;
    int c0 = blockIdx.y * 64;
    const float* src = in + (size_t)b * C * N;
    unsigned short* dst = out + (size_t)b * N * C;
    int t  = threadIdx.x;
    int t4 = t >> 6;   // 0..3
    int tn = t & 63;
#pragma unroll
    for (int i = 0; i < 16; ++i) {
        int cc = i * 4 + t4;
        tile[cc][tn] = src[(size_t)(c0 + cc) * N + n0 + tn];
    }
    __syncthreads();
#pragma unroll
    for (int i = 0; i < 16; ++i) {
        int nn = i * 4 + t4;
        dst[(size_t)(n0 + nn) * C + c0 + tn] = f2bf(tile[tn][nn]);
    }
}

// ---------------------------------------------------------------------------
// f32 -> bf16 convert (weights)
// ---------------------------------------------------------------------------
__global__ void k_cvt(const float* __restrict__ in, unsigned short* __restrict__ out, int n) {
    int i = blockIdx.x * 256 + threadIdx.x;
    if (i < n) out[i] = f2bf(in[i]);
}

// ---------------------------------------------------------------------------
// three_nn: per unknown point, 3 smallest squared distances (stable ties) +
// normalized inverse-distance weights. Match the reference expression
// d = u2 + k2 - 2*dot in plain f32 (no fma contraction).
// ---------------------------------------------------------------------------
__global__ void k_three_nn(const float* __restrict__ unknown, const float* __restrict__ known,
                           int* __restrict__ idx_out, float* __restrict__ w_out) {
    __shared__ float kx[MPTS], ky[MPTS], kz[MPTS], kd[MPTS];
    int b  = blockIdx.x >> 4;
    int p0 = (blockIdx.x & 15) * 256;
    const float* kb = known + (size_t)b * MPTS * 3;
    for (int i = threadIdx.x; i < MPTS; i += 256) {
        float x = kb[i * 3 + 0], y = kb[i * 3 + 1], z = kb[i * 3 + 2];
        kx[i] = x; ky[i] = y; kz[i] = z;
        kd[i] = __fadd_rn(__fadd_rn(__fmul_rn(x, x), __fmul_rn(y, y)), __fmul_rn(z, z));
    }
    __syncthreads();
    int p = p0 + threadIdx.x;
    const float* up = unknown + ((size_t)b * NPTS + p) * 3;
    float ux = up[0], uy = up[1], uz = up[2];
    float u2 = __fadd_rn(__fadd_rn(__fmul_rn(ux, ux), __fmul_rn(uy, uy)), __fmul_rn(uz, uz));
    float d0 = INFINITY, d1 = INFINITY, d2 = INFINITY;
    int   i0 = 0, i1 = 0, i2 = 0;
    for (int k = 0; k < MPTS; ++k) {
        float dot = __fadd_rn(__fadd_rn(__fmul_rn(ux, kx[k]), __fmul_rn(uy, ky[k])),
                              __fmul_rn(uz, kz[k]));
        float d = __fsub_rn(__fadd_rn(u2, kd[k]), __fmul_rn(2.0f, dot));
        if (d < d0)      { d2 = d1; i2 = i1; d1 = d0; i1 = i0; d0 = d; i0 = k; }
        else if (d < d1) { d2 = d1; i2 = i1; d1 = d;  i1 = k; }
        else if (d < d2) { d2 = d;  i2 = k; }
    }
    float r0 = 1.0f / (d0 + 1e-8f), r1 = 1.0f / (d1 + 1e-8f), r2 = 1.0f / (d2 + 1e-8f);
    float norm = r0 + r1 + r2;
    size_t pg = (size_t)b * NPTS + p;
    idx_out[pg * 3 + 0] = i0; idx_out[pg * 3 + 1] = i1; idx_out[pg * 3 + 2] = i2;
    w_out[pg * 3 + 0] = r0 / norm; w_out[pg * 3 + 1] = r1 / norm; w_out[pg * 3 + 2] = r2 / norm;
}

// ---------------------------------------------------------------------------
// GEMM: Y[p][co] = sum_k W[co][k] * X[p][k]  (+bias[co]).
// X is (PTOT, K) bf16 K-contiguous; W is (256, K) bf16; Y is (PTOT, 256) bf16.
// APPLY=1: during staging apply x <- relu(x*a + c) per channel (BN+relu of the
// previous layer fused into this GEMM's prologue).
// Block: 256 thr (4 waves), tile = 64 points x 256 out-channels, full-K LDS.
// ---------------------------------------------------------------------------
template <int K, int APPLY>
__global__ void k_gemm(const unsigned short* __restrict__ Wb,
                       const unsigned short* __restrict__ X,
                       const float* __restrict__ bias,
                       const float* __restrict__ aff_a,
                       const float* __restrict__ aff_c,
                       unsigned short* __restrict__ Y) {
    constexpr int KP = K + 8;                 // padded row in bf16 elems (row = (K+8)*2 bytes)
    __shared__ unsigned short Bs[64 * KP];
    int p0 = blockIdx.x * 64;
    int t  = threadIdx.x;

    // ---- stage 64 x K activation tile (contiguous global region) ----
    constexpr int CPR    = K / 8;             // 16B chunks per row
    constexpr int CHUNKS = 64 * CPR;
    const uint4* src = reinterpret_cast<const uint4*>(X + (size_t)p0 * K);
#pragma unroll
    for (int i = 0; i < CHUNKS / 256; ++i) {
        int f   = i * 256 + t;
        int row = f / CPR, col = f % CPR;
        uint4 v = src[f];
        if (APPLY) {
            unsigned int w[4] = {v.x, v.y, v.z, v.w};
#pragma unroll
            for (int q = 0; q < 4; ++q) {
                int c = col * 8 + q * 2;
                float lo = fmaxf(bf2f(w[q] & 0xffff) * aff_a[c]     + aff_c[c],     0.0f);
                float hi = fmaxf(bf2f(w[q] >> 16)    * aff_a[c + 1] + aff_c[c + 1], 0.0f);
                w[q] = (unsigned int)f2bf(lo) | ((unsigned int)f2bf(hi) << 16);
            }
            v.x = w[0]; v.y = w[1]; v.z = w[2]; v.w = w[3];
        }
        *reinterpret_cast<uint4*>(reinterpret_cast<char*>(Bs) + row * (KP * 2) + col * 16) = v;
    }
    __syncthreads();

    // ---- MFMA: each wave computes 64 out-channels x 64 points ----
    int wv = t >> 6, lane = t & 63;
    int lhi = lane >> 4, llo = lane & 15;
    f32x4 acc[4][4];
#pragma unroll
    for (int i = 0; i < 4; ++i)
#pragma unroll
        for (int j = 0; j < 4; ++j) acc[i][j] = (f32x4){0.f, 0.f, 0.f, 0.f};

#pragma unroll
    for (int ks = 0; ks < K / 32; ++ks) {
        int kk = ks * 32 + lhi * 8;
        bf16x8 a[4], bb[4];
#pragma unroll
        for (int i = 0; i < 4; ++i) {
            int row = wv * 64 + i * 16 + llo;   // out-channel
            a[i] = *reinterpret_cast<const bf16x8*>(Wb + (size_t)row * K + kk);
        }
#pragma unroll
        for (int j = 0; j < 4; ++j) {
            int row = j * 16 + llo;             // point
            bb[j] = *reinterpret_cast<const bf16x8*>(
                reinterpret_cast<const char*>(Bs) + row * (KP * 2) + kk * 2);
        }
#pragma unroll
        for (int i = 0; i < 4; ++i)
#pragma unroll
            for (int j = 0; j < 4; ++j)
                acc[i][j] = __builtin_amdgcn_mfma_f32_16x16x32_bf16(a[i], bb[j], acc[i][j], 0, 0, 0);
    }

    // ---- epilogue: +bias, cast bf16, store (p, co) ----
#pragma unroll
    for (int i = 0; i < 4; ++i) {
        int cbase = wv * 64 + i * 16 + lhi * 4;
        float b0 = bias[cbase], b1 = bias[cbase + 1], b2 = bias[cbase + 2], b3 = bias[cbase + 3];
#pragma unroll
        for (int j = 0; j < 4; ++j) {
            int p = p0 + j * 16 + llo;
            unsigned int lo = (unsigned int)f2bf(acc[i][j][0] + b0) |
                              ((unsigned int)f2bf(acc[i][j][1] + b1) << 16);
            unsigned int hi = (unsigned int)f2bf(acc[i][j][2] + b2) |
                              ((unsigned int)f2bf(acc[i][j][3] + b3) << 16);
            uint2 o; o.x = lo; o.y = hi;
            *reinterpret_cast<uint2*>(Y + (size_t)p * 256 + cbase) = o;
        }
    }
}

// ---------------------------------------------------------------------------
// BN stats pass 1: per-channel partial sum/sumsq over 256-row slabs.
// Deterministic (no atomics). Y is (PTOT, 256) bf16.
// ---------------------------------------------------------------------------
__global__ void k_stats(const unsigned short* __restrict__ Y, float* __restrict__ partial) {
    int c  = threadIdx.x;
    int r0 = blockIdx.x * 256;
    float s = 0.f, sq = 0.f;
    for (int r = 0; r < 256; ++r) {
        float v = bf2f(Y[(size_t)(r0 + r) * 256 + c]);
        s += v; sq += v * v;
    }
    partial[blockIdx.x * 512 + c]       = s;
    partial[blockIdx.x * 512 + 256 + c] = sq;
}

// BN stats pass 2: finalize into affine a = g*rsqrt(var+eps), c = beta - mean*a
__global__ void k_finalize(const float* __restrict__ partial, const float* __restrict__ gamma,
                           const float* __restrict__ beta, float* __restrict__ aff_a,
                           float* __restrict__ aff_c) {
    int c = threadIdx.x;
    float s = 0.f, sq = 0.f;
    for (int i = 0; i < 256; ++i) { s += partial[i * 512 + c]; sq += partial[i * 512 + 256 + c]; }
    float mean = s * (1.0f / PTOT);
    float var  = fmaxf(sq * (1.0f / PTOT) - mean * mean, 0.0f);
    float a    = gamma[c] / sqrtf(var + 1e-5f);
    aff_a[c] = a;
    aff_c[c] = beta[c] - mean * a;
}

// ---------------------------------------------------------------------------
// x[p][c] = sum_j w_j * kfT[b][idx_j][c]  +  (y0[p][c]*a0[c] + c0[c])
// (three_interpolate + BN(skip), fused). 32 threads/point, 8 ch/thread.
// ---------------------------------------------------------------------------
__global__ void k_build_x(const unsigned short* __restrict__ y0, const unsigned short* __restrict__ kfT,
                          const int* __restrict__ idx, const float* __restrict__ wgt,
                          const float* __restrict__ aff_a, const float* __restrict__ aff_c,
                          unsigned short* __restrict__ X) {
    int t  = threadIdx.x;
    int p  = blockIdx.x * 8 + (t >> 5);
    int c0 = (t & 31) * 8;
    int b  = p >> 12;
    int i0 = idx[p * 3 + 0], i1 = idx[p * 3 + 1], i2 = idx[p * 3 + 2];
    float w0 = wgt[p * 3 + 0], w1 = wgt[p * 3 + 1], w2 = wgt[p * 3 + 2];
    const size_t kb = (size_t)b * MPTS * C2;
    uint4 v0 = *reinterpret_cast<const uint4*>(kfT + kb + (size_t)i0 * C2 + c0);
    uint4 v1 = *reinterpret_cast<const uint4*>(kfT + kb + (size_t)i1 * C2 + c0);
    uint4 v2 = *reinterpret_cast<const uint4*>(kfT + kb + (size_t)i2 * C2 + c0);
    uint4 vy = *reinterpret_cast<const uint4*>(y0 + (size_t)p * C2 + c0);
    const unsigned int* u0 = reinterpret_cast<const unsigned int*>(&v0);
    const unsigned int* u1 = reinterpret_cast<const unsigned int*>(&v1);
    const unsigned int* u2 = reinterpret_cast<const unsigned int*>(&v2);
    const unsigned int* uy = reinterpret_cast<const unsigned int*>(&vy);
    unsigned int r[4];
#pragma unroll
    for (int q = 0; q < 4; ++q) {
        int c = c0 + q * 2;
        float lo = w0 * bf2f(u0[q] & 0xffff) + w1 * bf2f(u1[q] & 0xffff) + w2 * bf2f(u2[q] & 0xffff)
                 + bf2f(uy[q] & 0xffff) * aff_a[c] + aff_c[c];
        float hi = w0 * bf2f(u0[q] >> 16) + w1 * bf2f(u1[q] >> 16) + w2 * bf2f(u2[q] >> 16)
                 + bf2f(uy[q] >> 16) * aff_a[c + 1] + aff_c[c + 1];
        r[q] = (unsigned int)f2bf(lo) | ((unsigned int)f2bf(hi) << 16);
    }
    uint4 vout; vout.x = r[0]; vout.y = r[1]; vout.z = r[2]; vout.w = r[3];
    *reinterpret_cast<uint4*>(X + (size_t)p * C2 + c0) = vout;
}

// ---------------------------------------------------------------------------
// Final: out(B,256,n) f32 = relu(y2*a2+c2), transposed from (P,256) bf16.
// ---------------------------------------------------------------------------
__global__ void k_final(const unsigned short* __restrict__ Y2, const float* __restrict__ aff_a,
                        const float* __restrict__ aff_c, float* __restrict__ out) {
    __shared__ float tile[64][65];   // [c][p]
    int p0 = blockIdx.x * 64;
    int c0 = blockIdx.y * 64;
    int t  = threadIdx.x;
    int t4 = t >> 6, t64 = t & 63;
#pragma unroll
    for (int i = 0; i < 16; ++i) {
        int r = i * 4 + t4;               // point within tile
        int c = c0 + t64;
        float v = bf2f(Y2[(size_t)(p0 + r) * 256 + c]) * aff_a[c] + aff_c[c];
        tile[t64][r] = fmaxf(v, 0.0f);
    }
    __syncthreads();
    int b   = p0 >> 12;
    int pin = p0 & 4095;
#pragma unroll
    for (int i = 0; i < 16; ++i) {
        int cc = i * 4 + t4;
        out[((size_t)b * 256 + c0 + cc) * 4096 + pin + t64] = tile[cc][t64];
    }
}

// ---------------------------------------------------------------------------
extern "C" void kernel_launch(void* const* d_in, const int* in_sizes, int n_in,
                              void* d_out, int out_size, void* d_ws, size_t ws_size,
                              hipStream_t stream) {
    const float* unknown = (const float*)d_in[0];
    const float* known   = (const float*)d_in[1];
    const float* ufeat   = (const float*)d_in[2];
    const float* kfeat   = (const float*)d_in[3];
    const float* Wu      = (const float*)d_in[4];
    const float* bu      = (const float*)d_in[5];
    const float* gu      = (const float*)d_in[6];
    const float* betau   = (const float*)d_in[7];
    const float* W1      = (const float*)d_in[8];
    const float* b1      = (const float*)d_in[9];
    const float* g1      = (const float*)d_in[10];
    const float* beta1   = (const float*)d_in[11];
    const float* W2      = (const float*)d_in[12];
    const float* b2      = (const float*)d_in[13];
    const float* g2      = (const float*)d_in[14];
    const float* beta2   = (const float*)d_in[15];
    float* out = (float*)d_out;

    // workspace layout (~74.5 MB)
    char* ws = (char*)d_ws;
    unsigned short* reg0 = (unsigned short*)ws;                        // 32MB: uT -> x -> y2
    unsigned short* ybuf = (unsigned short*)(ws + ((size_t)32 << 20)); // 32MB: y0 -> y1
    unsigned short* kfT  = (unsigned short*)(ws + ((size_t)64 << 20)); // 8MB
    unsigned short* Wub  = (unsigned short*)(ws + ((size_t)72 << 20)); // 64KB
    unsigned short* W1b  = Wub + 256 * 128;                            // 128KB
    unsigned short* W2b  = W1b + 256 * 256;                            // 128KB
    int*   idxb = (int*)(W2b + 256 * 256);                             // 768KB
    float* wgtb = (float*)(idxb + (size_t)PTOT * 3);                   // 768KB
    float* part = wgtb + (size_t)PTOT * 3;                             // 512KB
    float* affa0 = part + 256 * 512;
    float* affc0 = affa0 + 256;
    float* affa1 = affc0 + 256;
    float* affc1 = affa1 + 256;
    float* affa2 = affc1 + 256;
    float* affc2 = affa2 + 256;
    if (ws_size < ((size_t)75 << 20)) return;   // need ~74.5MB scratch

    // 1) layout prep
    k_transpose<<<dim3(NPTS / 64, C1 / 64, BATCH), 256, 0, stream>>>(ufeat, reg0, C1, NPTS);
    k_transpose<<<dim3(MPTS / 64, C2 / 64, BATCH), 256, 0, stream>>>(kfeat, kfT, C2, MPTS);
    k_cvt<<<(256 * 128 + 255) / 256, 256, 0, stream>>>(Wu, Wub, 256 * 128);
    k_cvt<<<(256 * 256 + 255) / 256, 256, 0, stream>>>(W1, W1b, 256 * 256);
    k_cvt<<<(256 * 256 + 255) / 256, 256, 0, stream>>>(W2, W2b, 256 * 256);

    // 2) three_nn
    k_three_nn<<<256, 256, 0, stream>>>(unknown, known, idxb, wgtb);

    // 3) y0 = Wu @ uT + bu ; stats0
    k_gemm<C1, 0><<<PTOT / 64, 256, 0, stream>>>(Wub, reg0, bu, nullptr, nullptr, ybuf);
    k_stats<<<256, 256, 0, stream>>>(ybuf, part);
    k_finalize<<<1, 256, 0, stream>>>(part, gu, betau, affa0, affc0);

    // 4) x = interpolate + BN(y0)
    k_build_x<<<PTOT / 8, 256, 0, stream>>>(ybuf, kfT, idxb, wgtb, affa0, affc0, reg0);

    // 5) y1 = W1 @ x + b1 ; stats1
    k_gemm<C2, 0><<<PTOT / 64, 256, 0, stream>>>(W1b, reg0, b1, nullptr, nullptr, ybuf);
    k_stats<<<256, 256, 0, stream>>>(ybuf, part);
    k_finalize<<<1, 256, 0, stream>>>(part, g1, beta1, affa1, affc1);

    // 6) y2 = W2 @ relu(BN(y1)) + b2 ; stats2
    k_gemm<C2, 1><<<PTOT / 64, 256, 0, stream>>>(W2b, ybuf, b2, affa1, affc1, reg0);
    k_stats<<<256, 256, 0, stream>>>(reg0, part);
    k_finalize<<<1, 256, 0, stream>>>(part, g2, beta2, affa2, affc2);

    // 7) out = relu(BN(y2)) transposed to (B, 256, n) f32
    k_final<<<dim3(PTOT / 64, 4), 256, 0, stream>>>(reg0, affa2, affc2, out);

    (void)in_sizes; (void)n_in; (void)out_size; (void)ws_size;
}

// Round 2
// 287.846 us; speedup vs baseline: 1.4342x; 1.4342x over previous
//
#include <hip/hip_runtime.h>
#include <hip/hip_bf16.h>
#include <cstddef>

// Problem constants (from setup_inputs): B=16, n=4096, m=1024, C1=128, C2=C=256
#define BATCH 16
#define NPTS  4096
#define MPTS  1024
#define PTOT  65536      // BATCH*NPTS
#define C1    128
#define C2    256

typedef short bf16x8 __attribute__((ext_vector_type(8)));
typedef float f32x4  __attribute__((ext_vector_type(4)));

static __device__ __forceinline__ float bf2f(unsigned int u16) {
    union { unsigned int i; float f; } v; v.i = u16 << 16; return v.f;
}
static __device__ __forceinline__ unsigned short f2bf(float f) {
    union { float f; unsigned int i; } v; v.f = f;
    unsigned int u = v.i;
    return (unsigned short)((u + 0x7FFFu + ((u >> 16) & 1u)) >> 16);
}

// ---------------------------------------------------------------------------
// Transpose (B, C, N) f32  ->  (B, N, C) bf16
// ---------------------------------------------------------------------------
__global__ void k_transpose(const float* __restrict__ in, unsigned short* __restrict__ out,
                            int C, int N) {
    __shared__ float tile[64][65];
    int b  = blockIdx.z;
    int n0 = blockIdx.x * 64;
    int c0 = blockIdx.y * 64;
    const float* src = in + (size_t)b * C * N;
    unsigned short* dst = out + (size_t)b * N * C;
    int t  = threadIdx.x;
    int t4 = t >> 6;   // 0..3
    int tn = t & 63;
#pragma unroll
    for (int i = 0; i < 16; ++i) {
        int cc = i * 4 + t4;
        tile[cc][tn] = src[(size_t)(c0 + cc) * N + n0 + tn];
    }
    __syncthreads();
#pragma unroll
    for (int i = 0; i < 16; ++i) {
        int nn = i * 4 + t4;
        dst[(size_t)(n0 + nn) * C + c0 + tn] = f2bf(tile[tn][nn]);
    }
}

// ---------------------------------------------------------------------------
// f32 -> bf16 convert (weights)
// ---------------------------------------------------------------------------
__global__ void k_cvt(const float* __restrict__ in, unsigned short* __restrict__ out, int n) {
    int i = blockIdx.x * 256 + threadIdx.x;
    if (i < n) out[i] = f2bf(in[i]);
}

// ---------------------------------------------------------------------------
// three_nn, parallel version: 4 threads per point, each scans a 256-point
// chunk keeping a local top-3, then a 2-step shfl_xor butterfly merge with
// (d, idx) lexicographic comparator (matches top_k lowest-index tie-break).
// Distance expression is bit-exact with the reference: u2 + k2 - 2*dot, all
// ops rounded (no fma contraction).
// Block = 256 thr handles 64 points; grid = PTOT/64 = 1024 blocks.
// ---------------------------------------------------------------------------
static __device__ __forceinline__ bool nn_less(float da, int ia, float db, int ib) {
    return (da < db) || (da == db && ia < ib);
}

__global__ void k_three_nn(const float* __restrict__ unknown, const float* __restrict__ known,
                           int* __restrict__ idx_out, float* __restrict__ w_out) {
    __shared__ float4 kpt[MPTS + 4];    // slot(k) = k + (k>>8): chunk bases on banks 0/4/8/12
    int t  = threadIdx.x;
    int p0 = blockIdx.x * 64;
    int b  = p0 >> 12;                  // 64 points never straddle a batch (4096 % 64 == 0)
    const float* kb = known + (size_t)b * MPTS * 3;
    for (int i = t; i < MPTS; i += 256) {
        float x = kb[i * 3 + 0], y = kb[i * 3 + 1], z = kb[i * 3 + 2];
        float dd = __fadd_rn(__fadd_rn(__fmul_rn(x, x), __fmul_rn(y, y)), __fmul_rn(z, z));
        float4 v; v.x = x; v.y = y; v.z = z; v.w = dd;
        kpt[i + (i >> 8)] = v;
    }
    __syncthreads();

    int q = t & 3;                      // chunk id
    int p = p0 + (t >> 2);
    const float* up = unknown + (size_t)p * 3;
    float ux = up[0], uy = up[1], uz = up[2];
    float u2 = __fadd_rn(__fadd_rn(__fmul_rn(ux, ux), __fmul_rn(uy, uy)), __fmul_rn(uz, uz));

    float d0 = INFINITY, d1 = INFINITY, d2 = INFINITY;
    int   i0 = 0, i1 = 0, i2 = 0;
    int base = q * 257;                 // slot of k = q*256
#pragma unroll 4
    for (int it = 0; it < 256; ++it) {
        float4 kp = kpt[base + it];
        float dot = __fadd_rn(__fadd_rn(__fmul_rn(ux, kp.x), __fmul_rn(uy, kp.y)),
                              __fmul_rn(uz, kp.z));
        float d = __fsub_rn(__fadd_rn(u2, kp.w), __fmul_rn(2.0f, dot));
        int k = q * 256 + it;
        if (d < d0)      { d2 = d1; i2 = i1; d1 = d0; i1 = i0; d0 = d; i0 = k; }
        else if (d < d1) { d2 = d1; i2 = i1; d1 = d;  i1 = k; }
        else if (d < d2) { d2 = d;  i2 = k; }
    }

    // butterfly merge across the 4 chunk-lanes
#pragma unroll
    for (int m = 1; m <= 2; m <<= 1) {
        float e0 = __shfl_xor(d0, m, 64), e1 = __shfl_xor(d1, m, 64), e2 = __shfl_xor(d2, m, 64);
        int   j0 = __shfl_xor(i0, m, 64), j1 = __shfl_xor(i1, m, 64), j2 = __shfl_xor(i2, m, 64);
        float a0 = d0, a1 = d1, a2 = d2; int x0 = i0, x1 = i1, x2 = i2;
        float b0 = e0, b1 = e1, b2 = e2; int y0 = j0, y1 = j1, y2 = j2;
        bool tk = nn_less(a0, x0, b0, y0);
        d0 = tk ? a0 : b0; i0 = tk ? x0 : y0;
        float na0 = tk ? a1 : a0; int nx0 = tk ? x1 : x0;
        float na1 = tk ? a2 : a1; int nx1 = tk ? x2 : x1;
        float nb0 = tk ? b0 : b1; int ny0 = tk ? y0 : y1;
        float nb1 = tk ? b1 : b2; int ny1 = tk ? y1 : y2;
        tk = nn_less(na0, nx0, nb0, ny0);
        d1 = tk ? na0 : nb0; i1 = tk ? nx0 : ny0;
        float ma0 = tk ? na1 : na0; int mx0 = tk ? nx1 : nx0;
        float mb0 = tk ? nb0 : nb1; int my0 = tk ? ny0 : ny1;
        tk = nn_less(ma0, mx0, mb0, my0);
        d2 = tk ? ma0 : mb0; i2 = tk ? mx0 : my0;
    }

    if (q == 0) {
        float r0 = 1.0f / (d0 + 1e-8f), r1 = 1.0f / (d1 + 1e-8f), r2 = 1.0f / (d2 + 1e-8f);
        float norm = r0 + r1 + r2;
        size_t pg = (size_t)p;
        idx_out[pg * 3 + 0] = i0; idx_out[pg * 3 + 1] = i1; idx_out[pg * 3 + 2] = i2;
        w_out[pg * 3 + 0] = r0 / norm; w_out[pg * 3 + 1] = r1 / norm; w_out[pg * 3 + 2] = r2 / norm;
    }
}

// ---------------------------------------------------------------------------
// GEMM: Y[p][co] = sum_k W[co][k] * X[p][k]  (+bias[co]).
// X is (PTOT, K) bf16 K-contiguous; W is (256, K) bf16; Y is (PTOT, 256) bf16.
// APPLY=1: during staging apply x <- relu(x*a + c) per channel (BN+relu of the
// previous layer fused into this GEMM's prologue).
// Block: 256 thr (4 waves), tile = 64 points x 256 out-channels, full-K LDS.
// ---------------------------------------------------------------------------
template <int K, int APPLY>
__global__ void k_gemm(const unsigned short* __restrict__ Wb,
                       const unsigned short* __restrict__ X,
                       const float* __restrict__ bias,
                       const float* __restrict__ aff_a,
                       const float* __restrict__ aff_c,
                       unsigned short* __restrict__ Y) {
    constexpr int KP = K + 8;                 // padded row in bf16 elems (row = (K+8)*2 bytes)
    __shared__ unsigned short Bs[64 * KP];
    int p0 = blockIdx.x * 64;
    int t  = threadIdx.x;

    // ---- stage 64 x K activation tile (contiguous global region) ----
    constexpr int CPR    = K / 8;             // 16B chunks per row
    constexpr int CHUNKS = 64 * CPR;
    const uint4* src = reinterpret_cast<const uint4*>(X + (size_t)p0 * K);
#pragma unroll
    for (int i = 0; i < CHUNKS / 256; ++i) {
        int f   = i * 256 + t;
        int row = f / CPR, col = f % CPR;
        uint4 v = src[f];
        if (APPLY) {
            unsigned int w[4] = {v.x, v.y, v.z, v.w};
#pragma unroll
            for (int q = 0; q < 4; ++q) {
                int c = col * 8 + q * 2;
                float lo = fmaxf(bf2f(w[q] & 0xffff) * aff_a[c]     + aff_c[c],     0.0f);
                float hi = fmaxf(bf2f(w[q] >> 16)    * aff_a[c + 1] + aff_c[c + 1], 0.0f);
                w[q] = (unsigned int)f2bf(lo) | ((unsigned int)f2bf(hi) << 16);
            }
            v.x = w[0]; v.y = w[1]; v.z = w[2]; v.w = w[3];
        }
        *reinterpret_cast<uint4*>(reinterpret_cast<char*>(Bs) + row * (KP * 2) + col * 16) = v;
    }
    __syncthreads();

    // ---- MFMA: each wave computes 64 out-channels x 64 points ----
    int wv = t >> 6, lane = t & 63;
    int lhi = lane >> 4, llo = lane & 15;
    f32x4 acc[4][4];
#pragma unroll
    for (int i = 0; i < 4; ++i)
#pragma unroll
        for (int j = 0; j < 4; ++j) acc[i][j] = (f32x4){0.f, 0.f, 0.f, 0.f};

#pragma unroll
    for (int ks = 0; ks < K / 32; ++ks) {
        int kk = ks * 32 + lhi * 8;
        bf16x8 a[4], bb[4];
#pragma unroll
        for (int i = 0; i < 4; ++i) {
            int row = wv * 64 + i * 16 + llo;   // out-channel
            a[i] = *reinterpret_cast<const bf16x8*>(Wb + (size_t)row * K + kk);
        }
#pragma unroll
        for (int j = 0; j < 4; ++j) {
            int row = j * 16 + llo;             // point
            bb[j] = *reinterpret_cast<const bf16x8*>(
                reinterpret_cast<const char*>(Bs) + row * (KP * 2) + kk * 2);
        }
#pragma unroll
        for (int i = 0; i < 4; ++i)
#pragma unroll
            for (int j = 0; j < 4; ++j)
                acc[i][j] = __builtin_amdgcn_mfma_f32_16x16x32_bf16(a[i], bb[j], acc[i][j], 0, 0, 0);
    }

    // ---- epilogue: +bias, cast bf16, store (p, co) ----
#pragma unroll
    for (int i = 0; i < 4; ++i) {
        int cbase = wv * 64 + i * 16 + lhi * 4;
        float b0 = bias[cbase], b1 = bias[cbase + 1], b2 = bias[cbase + 2], b3 = bias[cbase + 3];
#pragma unroll
        for (int j = 0; j < 4; ++j) {
            int p = p0 + j * 16 + llo;
            unsigned int lo = (unsigned int)f2bf(acc[i][j][0] + b0) |
                              ((unsigned int)f2bf(acc[i][j][1] + b1) << 16);
            unsigned int hi = (unsigned int)f2bf(acc[i][j][2] + b2) |
                              ((unsigned int)f2bf(acc[i][j][3] + b3) << 16);
            uint2 o; o.x = lo; o.y = hi;
            *reinterpret_cast<uint2*>(Y + (size_t)p * 256 + cbase) = o;
        }
    }
}

// ---------------------------------------------------------------------------
// BN stats pass 1: per-channel partial sum/sumsq over 256-row slabs.
// Deterministic (no atomics). Y is (PTOT, 256) bf16.
// ---------------------------------------------------------------------------
__global__ void k_stats(const unsigned short* __restrict__ Y, float* __restrict__ partial) {
    int c  = threadIdx.x;
    int r0 = blockIdx.x * 256;
    float s = 0.f, sq = 0.f;
    for (int r = 0; r < 256; ++r) {
        float v = bf2f(Y[(size_t)(r0 + r) * 256 + c]);
        s += v; sq += v * v;
    }
    partial[blockIdx.x * 512 + c]       = s;
    partial[blockIdx.x * 512 + 256 + c] = sq;
}

// BN stats pass 2: finalize into affine a = g*rsqrt(var+eps), c = beta - mean*a
__global__ void k_finalize(const float* __restrict__ partial, const float* __restrict__ gamma,
                           const float* __restrict__ beta, float* __restrict__ aff_a,
                           float* __restrict__ aff_c) {
    int c = threadIdx.x;
    float s = 0.f, sq = 0.f;
    for (int i = 0; i < 256; ++i) { s += partial[i * 512 + c]; sq += partial[i * 512 + 256 + c]; }
    float mean = s * (1.0f / PTOT);
    float var  = fmaxf(sq * (1.0f / PTOT) - mean * mean, 0.0f);
    float a    = gamma[c] / sqrtf(var + 1e-5f);
    aff_a[c] = a;
    aff_c[c] = beta[c] - mean * a;
}

// ---------------------------------------------------------------------------
// x[p][c] = sum_j w_j * kfT[b][idx_j][c]  +  (y0[p][c]*a0[c] + c0[c])
// (three_interpolate + BN(skip), fused). 32 threads/point, 8 ch/thread.
// ---------------------------------------------------------------------------
__global__ void k_build_x(const unsigned short* __restrict__ y0, const unsigned short* __restrict__ kfT,
                          const int* __restrict__ idx, const float* __restrict__ wgt,
                          const float* __restrict__ aff_a, const float* __restrict__ aff_c,
                          unsigned short* __restrict__ X) {
    int t  = threadIdx.x;
    int p  = blockIdx.x * 8 + (t >> 5);
    int c0 = (t & 31) * 8;
    int b  = p >> 12;
    int i0 = idx[p * 3 + 0], i1 = idx[p * 3 + 1], i2 = idx[p * 3 + 2];
    float w0 = wgt[p * 3 + 0], w1 = wgt[p * 3 + 1], w2 = wgt[p * 3 + 2];
    const size_t kb = (size_t)b * MPTS * C2;
    uint4 v0 = *reinterpret_cast<const uint4*>(kfT + kb + (size_t)i0 * C2 + c0);
    uint4 v1 = *reinterpret_cast<const uint4*>(kfT + kb + (size_t)i1 * C2 + c0);
    uint4 v2 = *reinterpret_cast<const uint4*>(kfT + kb + (size_t)i2 * C2 + c0);
    uint4 vy = *reinterpret_cast<const uint4*>(y0 + (size_t)p * C2 + c0);
    const unsigned int* u0 = reinterpret_cast<const unsigned int*>(&v0);
    const unsigned int* u1 = reinterpret_cast<const unsigned int*>(&v1);
    const unsigned int* u2 = reinterpret_cast<const unsigned int*>(&v2);
    const unsigned int* uy = reinterpret_cast<const unsigned int*>(&vy);
    unsigned int r[4];
#pragma unroll
    for (int q = 0; q < 4; ++q) {
        int c = c0 + q * 2;
        float lo = w0 * bf2f(u0[q] & 0xffff) + w1 * bf2f(u1[q] & 0xffff) + w2 * bf2f(u2[q] & 0xffff)
                 + bf2f(uy[q] & 0xffff) * aff_a[c] + aff_c[c];
        float hi = w0 * bf2f(u0[q] >> 16) + w1 * bf2f(u1[q] >> 16) + w2 * bf2f(u2[q] >> 16)
                 + bf2f(uy[q] >> 16) * aff_a[c + 1] + aff_c[c + 1];
        r[q] = (unsigned int)f2bf(lo) | ((unsigned int)f2bf(hi) << 16);
    }
    uint4 vout; vout.x = r[0]; vout.y = r[1]; vout.z = r[2]; vout.w = r[3];
    *reinterpret_cast<uint4*>(X + (size_t)p * C2 + c0) = vout;
}

// ---------------------------------------------------------------------------
// Final: out(B,256,n) f32 = relu(y2*a2+c2), transposed from (P,256) bf16.
// ---------------------------------------------------------------------------
__global__ void k_final(const unsigned short* __restrict__ Y2, const float* __restrict__ aff_a,
                        const float* __restrict__ aff_c, float* __restrict__ out) {
    __shared__ float tile[64][65];   // [c][p]
    int p0 = blockIdx.x * 64;
    int c0 = blockIdx.y * 64;
    int t  = threadIdx.x;
    int t4 = t >> 6, t64 = t & 63;
#pragma unroll
    for (int i = 0; i < 16; ++i) {
        int r = i * 4 + t4;               // point within tile
        int c = c0 + t64;
        float v = bf2f(Y2[(size_t)(p0 + r) * 256 + c]) * aff_a[c] + aff_c[c];
        tile[t64][r] = fmaxf(v, 0.0f);
    }
    __syncthreads();
    int b   = p0 >> 12;
    int pin = p0 & 4095;
#pragma unroll
    for (int i = 0; i < 16; ++i) {
        int cc = i * 4 + t4;
        out[((size_t)b * 256 + c0 + cc) * 4096 + pin + t64] = tile[cc][t64];
    }
}

// ---------------------------------------------------------------------------
extern "C" void kernel_launch(void* const* d_in, const int* in_sizes, int n_in,
                              void* d_out, int out_size, void* d_ws, size_t ws_size,
                              hipStream_t stream) {
    const float* unknown = (const float*)d_in[0];
    const float* known   = (const float*)d_in[1];
    const float* ufeat   = (const float*)d_in[2];
    const float* kfeat   = (const float*)d_in[3];
    const float* Wu      = (const float*)d_in[4];
    const float* bu      = (const float*)d_in[5];
    const float* gu      = (const float*)d_in[6];
    const float* betau   = (const float*)d_in[7];
    const float* W1      = (const float*)d_in[8];
    const float* b1      = (const float*)d_in[9];
    const float* g1      = (const float*)d_in[10];
    const float* beta1   = (const float*)d_in[11];
    const float* W2      = (const float*)d_in[12];
    const float* b2      = (const float*)d_in[13];
    const float* g2      = (const float*)d_in[14];
    const float* beta2   = (const float*)d_in[15];
    float* out = (float*)d_out;

    // workspace layout (~74.5 MB)
    char* ws = (char*)d_ws;
    unsigned short* reg0 = (unsigned short*)ws;                        // 32MB: uT -> x -> y2
    unsigned short* ybuf = (unsigned short*)(ws + ((size_t)32 << 20)); // 32MB: y0 -> y1
    unsigned short* kfT  = (unsigned short*)(ws + ((size_t)64 << 20)); // 8MB
    unsigned short* Wub  = (unsigned short*)(ws + ((size_t)72 << 20)); // 64KB
    unsigned short* W1b  = Wub + 256 * 128;                            // 128KB
    unsigned short* W2b  = W1b + 256 * 256;                            // 128KB
    int*   idxb = (int*)(W2b + 256 * 256);                             // 768KB
    float* wgtb = (float*)(idxb + (size_t)PTOT * 3);                   // 768KB
    float* part = wgtb + (size_t)PTOT * 3;                             // 512KB
    float* affa0 = part + 256 * 512;
    float* affc0 = affa0 + 256;
    float* affa1 = affc0 + 256;
    float* affc1 = affa1 + 256;
    float* affa2 = affc1 + 256;
    float* affc2 = affa2 + 256;
    if (ws_size < ((size_t)75 << 20)) return;   // need ~74.5MB scratch

    // 1) layout prep
    k_transpose<<<dim3(NPTS / 64, C1 / 64, BATCH), 256, 0, stream>>>(ufeat, reg0, C1, NPTS);
    k_transpose<<<dim3(MPTS / 64, C2 / 64, BATCH), 256, 0, stream>>>(kfeat, kfT, C2, MPTS);
    k_cvt<<<(256 * 128 + 255) / 256, 256, 0, stream>>>(Wu, Wub, 256 * 128);
    k_cvt<<<(256 * 256 + 255) / 256, 256, 0, stream>>>(W1, W1b, 256 * 256);
    k_cvt<<<(256 * 256 + 255) / 256, 256, 0, stream>>>(W2, W2b, 256 * 256);

    // 2) three_nn (parallel: 4 threads/point, 64 points/block)
    k_three_nn<<<PTOT / 64, 256, 0, stream>>>(unknown, known, idxb, wgtb);

    // 3) y0 = Wu @ uT + bu ; stats0
    k_gemm<C1, 0><<<PTOT / 64, 256, 0, stream>>>(Wub, reg0, bu, nullptr, nullptr, ybuf);
    k_stats<<<256, 256, 0, stream>>>(ybuf, part);
    k_finalize<<<1, 256, 0, stream>>>(part, gu, betau, affa0, affc0);

    // 4) x = interpolate + BN(y0)
    k_build_x<<<PTOT / 8, 256, 0, stream>>>(ybuf, kfT, idxb, wgtb, affa0, affc0, reg0);

    // 5) y1 = W1 @ x + b1 ; stats1
    k_gemm<C2, 0><<<PTOT / 64, 256, 0, stream>>>(W1b, reg0, b1, nullptr, nullptr, ybuf);
    k_stats<<<256, 256, 0, stream>>>(ybuf, part);
    k_finalize<<<1, 256, 0, stream>>>(part, g1, beta1, affa1, affc1);

    // 6) y2 = W2 @ relu(BN(y1)) + b2 ; stats2
    k_gemm<C2, 1><<<PTOT / 64, 256, 0, stream>>>(W2b, ybuf, b2, affa1, affc1, reg0);
    k_stats<<<256, 256, 0, stream>>>(reg0, part);
    k_finalize<<<1, 256, 0, stream>>>(part, g2, beta2, affa2, affc2);

    // 7) out = relu(BN(y2)) transposed to (B, 256, n) f32
    k_final<<<dim3(PTOT / 64, 4), 256, 0, stream>>>(reg0, affa2, affc2, out);

    (void)in_sizes; (void)n_in; (void)out_size; (void)ws_size;
}

// Round 3
// 225.607 us; speedup vs baseline: 1.8298x; 1.2759x over previous
//
#include <hip/hip_runtime.h>
#include <hip/hip_bf16.h>
#include <cstddef>
#include <cstdint>

// Problem constants (from setup_inputs): B=16, n=4096, m=1024, C1=128, C2=C=256
#define BATCH 16
#define NPTS  4096
#define MPTS  1024
#define PTOT  65536      // BATCH*NPTS
#define C1    128
#define C2    256

typedef short bf16x8 __attribute__((ext_vector_type(8)));
typedef float f32x4  __attribute__((ext_vector_type(4)));

static __device__ __forceinline__ float bf2f(unsigned int u16) {
    union { unsigned int i; float f; } v; v.i = u16 << 16; return v.f;
}
static __device__ __forceinline__ unsigned short f2bf(float f) {
    union { float f; unsigned int i; } v; v.f = f;
    unsigned int u = v.i;
    return (unsigned short)((u + 0x7FFFu + ((u >> 16) & 1u)) >> 16);
}

// Swizzled activation layout: (P, C) bf16 rows; within each row the 16B
// chunks (8 channels) are stored at position chunk ^ (p & 7). This makes a
// linear global_load_lds image of a 64-row tile read conflict-free by
// ds_read_b128 column slices (2-way only). Both-sides-or-neither (rule #21).

// ---------------------------------------------------------------------------
// Transpose (B, C, N) f32 -> (B, N, C) bf16. SWZ=1: chunk-swizzled rows.
// ---------------------------------------------------------------------------
template <int SWZ>
__global__ void k_transpose(const float* __restrict__ in, unsigned short* __restrict__ out,
                            int C, int N) {
    __shared__ float tile[64][65];
    int b  = blockIdx.z;
    int n0 = blockIdx.x * 64;
    int c0 = blockIdx.y * 64;
    const float* src = in + (size_t)b * C * N;
    unsigned short* dst = out + (size_t)b * N * C;
    int t  = threadIdx.x;
    int t4 = t >> 6;   // 0..3
    int tn = t & 63;
#pragma unroll
    for (int i = 0; i < 16; ++i) {
        int cc = i * 4 + t4;
        tile[cc][tn] = src[(size_t)(c0 + cc) * N + n0 + tn];
    }
    __syncthreads();
#pragma unroll
    for (int i = 0; i < 16; ++i) {
        int nn = i * 4 + t4;
        int p  = n0 + nn;
        int c  = c0 + tn;
        size_t off;
        if (SWZ) off = (size_t)p * C + (size_t)((((c >> 3) ^ (p & 7)) << 3) + (c & 7));
        else     off = (size_t)p * C + c;
        dst[off] = f2bf(tile[tn][nn]);
    }
}

// ---------------------------------------------------------------------------
// f32 -> bf16 convert (weights, linear)
// ---------------------------------------------------------------------------
__global__ void k_cvt(const float* __restrict__ in, unsigned short* __restrict__ out, int n) {
    int i = blockIdx.x * 256 + threadIdx.x;
    if (i < n) out[i] = f2bf(in[i]);
}

// ---------------------------------------------------------------------------
// three_nn: 4 threads/point, chunked scan + shfl_xor butterfly merge with
// (d, idx) lexicographic comparator. Distance expr bit-exact with reference.
// ---------------------------------------------------------------------------
static __device__ __forceinline__ bool nn_less(float da, int ia, float db, int ib) {
    return (da < db) || (da == db && ia < ib);
}

__global__ void k_three_nn(const float* __restrict__ unknown, const float* __restrict__ known,
                           int* __restrict__ idx_out, float* __restrict__ w_out) {
    __shared__ float4 kpt[MPTS + 4];
    int t  = threadIdx.x;
    int p0 = blockIdx.x * 64;
    int b  = p0 >> 12;
    const float* kb = known + (size_t)b * MPTS * 3;
    for (int i = t; i < MPTS; i += 256) {
        float x = kb[i * 3 + 0], y = kb[i * 3 + 1], z = kb[i * 3 + 2];
        float dd = __fadd_rn(__fadd_rn(__fmul_rn(x, x), __fmul_rn(y, y)), __fmul_rn(z, z));
        float4 v; v.x = x; v.y = y; v.z = z; v.w = dd;
        kpt[i + (i >> 8)] = v;
    }
    __syncthreads();

    int q = t & 3;
    int p = p0 + (t >> 2);
    const float* up = unknown + (size_t)p * 3;
    float ux = up[0], uy = up[1], uz = up[2];
    float u2 = __fadd_rn(__fadd_rn(__fmul_rn(ux, ux), __fmul_rn(uy, uy)), __fmul_rn(uz, uz));

    float d0 = INFINITY, d1 = INFINITY, d2 = INFINITY;
    int   i0 = 0, i1 = 0, i2 = 0;
    int base = q * 257;
#pragma unroll 4
    for (int it = 0; it < 256; ++it) {
        float4 kp = kpt[base + it];
        float dot = __fadd_rn(__fadd_rn(__fmul_rn(ux, kp.x), __fmul_rn(uy, kp.y)),
                              __fmul_rn(uz, kp.z));
        float d = __fsub_rn(__fadd_rn(u2, kp.w), __fmul_rn(2.0f, dot));
        int k = q * 256 + it;
        if (d < d0)      { d2 = d1; i2 = i1; d1 = d0; i1 = i0; d0 = d; i0 = k; }
        else if (d < d1) { d2 = d1; i2 = i1; d1 = d;  i1 = k; }
        else if (d < d2) { d2 = d;  i2 = k; }
    }

#pragma unroll
    for (int m = 1; m <= 2; m <<= 1) {
        float e0 = __shfl_xor(d0, m, 64), e1 = __shfl_xor(d1, m, 64), e2 = __shfl_xor(d2, m, 64);
        int   j0 = __shfl_xor(i0, m, 64), j1 = __shfl_xor(i1, m, 64), j2 = __shfl_xor(i2, m, 64);
        float a0 = d0, a1 = d1, a2 = d2; int x0 = i0, x1 = i1, x2 = i2;
        float b0 = e0, b1 = e1, b2 = e2; int y0 = j0, y1 = j1, y2 = j2;
        bool tk = nn_less(a0, x0, b0, y0);
        d0 = tk ? a0 : b0; i0 = tk ? x0 : y0;
        float na0 = tk ? a1 : a0; int nx0 = tk ? x1 : x0;
        float na1 = tk ? a2 : a1; int nx1 = tk ? x2 : x1;
        float nb0 = tk ? b0 : b1; int ny0 = tk ? y0 : y1;
        float nb1 = tk ? b1 : b2; int ny1 = tk ? y1 : y2;
        tk = nn_less(na0, nx0, nb0, ny0);
        d1 = tk ? na0 : nb0; i1 = tk ? nx0 : ny0;
        float ma0 = tk ? na1 : na0; int mx0 = tk ? nx1 : nx0;
        float mb0 = tk ? nb0 : nb1; int my0 = tk ? ny0 : ny1;
        tk = nn_less(ma0, mx0, mb0, my0);
        d2 = tk ? ma0 : mb0; i2 = tk ? mx0 : my0;
    }

    if (q == 0) {
        float r0 = 1.0f / (d0 + 1e-8f), r1 = 1.0f / (d1 + 1e-8f), r2 = 1.0f / (d2 + 1e-8f);
        float norm = r0 + r1 + r2;
        size_t pg = (size_t)p;
        idx_out[pg * 3 + 0] = i0; idx_out[pg * 3 + 1] = i1; idx_out[pg * 3 + 2] = i2;
        w_out[pg * 3 + 0] = r0 / norm; w_out[pg * 3 + 1] = r1 / norm; w_out[pg * 3 + 2] = r2 / norm;
    }
}

// ---------------------------------------------------------------------------
// GEMM: Y[p][co] = sum_k W[co][k] * X[p][k] + bias[co].
// X: (PTOT, K) bf16, chunk-swizzled rows. W: (256, K) bf16 linear.
// Y: (PTOT, 256) bf16, chunk-swizzled. Fused per-block BN partial stats.
// APPLY=1: x <- relu(x*aff_a + aff_c) applied during (manual) staging.
// Block: 256 thr (4 waves), tile = 64 points x 256 out-channels, full K.
// Weight panel prefetched to registers; X tile staged via global_load_lds
// (APPLY=0) so the only stall is one overlapped staging wait per block.
// ---------------------------------------------------------------------------
template <int K, int APPLY>
__global__ __launch_bounds__(256, 2) void k_gemm(
        const unsigned short* __restrict__ Wb,
        const unsigned short* __restrict__ X,
        const float* __restrict__ bias,
        const float* __restrict__ aff_a,
        const float* __restrict__ aff_c,
        unsigned short* __restrict__ Y,
        float* __restrict__ partial) {
    constexpr int RED_BYTES  = 2 * 16 * 257 * 4;
    constexpr int TILE_BYTES = 64 * K * 2;
    constexpr int SMEM_BYTES = TILE_BYTES > RED_BYTES ? TILE_BYTES : RED_BYTES;
    __shared__ char smem[SMEM_BYTES];

    const int t    = threadIdx.x;
    const int p0   = blockIdx.x * 64;
    const int wv   = t >> 6;
    const int lane = t & 63;
    const int lhi  = lane >> 4, llo = lane & 15;

    // ---- stage 64 x K activation tile into LDS (swizzled image) ----
    if (!APPLY) {
        const char* src = (const char*)(X + (size_t)p0 * K);
        constexpr int ITERS = TILE_BYTES / (256 * 16);
#pragma unroll
        for (int i = 0; i < ITERS; ++i) {
            int off = (i * 256 + t) * 16;
            __builtin_amdgcn_global_load_lds(
                (const __attribute__((address_space(1))) unsigned int*)(src + off),
                (__attribute__((address_space(3))) unsigned int*)(smem + off),
                16, 0, 0);
        }
    } else {
        constexpr int CPR = K / 8;    // 16B chunks per row
#pragma unroll
        for (int i = 0; i < (64 * CPR) / 256; ++i) {
            int f   = i * 256 + t;
            int row = f / CPR, qp = f % CPR;     // qp = stored (swizzled) position
            int col = qp ^ (row & 7);            // logical chunk -> channels col*8..+7
            uint4 v = *(const uint4*)(X + (size_t)(p0 + row) * K + qp * 8);
            unsigned int w[4] = {v.x, v.y, v.z, v.w};
            float4 a0 = *(const float4*)(aff_a + col * 8);
            float4 a1 = *(const float4*)(aff_a + col * 8 + 4);
            float4 cc0 = *(const float4*)(aff_c + col * 8);
            float4 cc1 = *(const float4*)(aff_c + col * 8 + 4);
            float aa[8] = {a0.x, a0.y, a0.z, a0.w, a1.x, a1.y, a1.z, a1.w};
            float cc[8] = {cc0.x, cc0.y, cc0.z, cc0.w, cc1.x, cc1.y, cc1.z, cc1.w};
#pragma unroll
            for (int q2 = 0; q2 < 4; ++q2) {
                float lo = fmaxf(bf2f(w[q2] & 0xffff) * aa[q2 * 2]     + cc[q2 * 2],     0.0f);
                float hi = fmaxf(bf2f(w[q2] >> 16)    * aa[q2 * 2 + 1] + cc[q2 * 2 + 1], 0.0f);
                w[q2] = (unsigned int)f2bf(lo) | ((unsigned int)f2bf(hi) << 16);
            }
            uint4 o; o.x = w[0]; o.y = w[1]; o.z = w[2]; o.w = w[3];
            *(uint4*)(smem + row * (K * 2) + qp * 16) = o;
        }
    }

    // ---- weight panel to registers (independent loads; overlap staging) ----
    bf16x8 wf[K / 32][4];
#pragma unroll
    for (int ks = 0; ks < K / 32; ++ks)
#pragma unroll
        for (int i = 0; i < 4; ++i) {
            int ch = wv * 64 + i * 16 + llo;
            wf[ks][i] = *(const bf16x8*)(Wb + (size_t)ch * K + ks * 32 + lhi * 8);
        }

    __syncthreads();

    // ---- MFMA: each wave computes 64 out-channels x 64 points ----
    f32x4 acc[4][4];
#pragma unroll
    for (int i = 0; i < 4; ++i)
#pragma unroll
        for (int j = 0; j < 4; ++j) acc[i][j] = (f32x4){0.f, 0.f, 0.f, 0.f};

#pragma unroll
    for (int ks = 0; ks < K / 32; ++ks) {
        bf16x8 bb[4];
#pragma unroll
        for (int j = 0; j < 4; ++j) {
            int row = j * 16 + llo;
            int cp  = (ks * 4 + lhi) ^ (row & 7);
            bb[j] = *(const bf16x8*)(smem + row * (K * 2) + cp * 16);
        }
#pragma unroll
        for (int i = 0; i < 4; ++i)
#pragma unroll
            for (int j = 0; j < 4; ++j)
                acc[i][j] = __builtin_amdgcn_mfma_f32_16x16x32_bf16(wf[ks][i], bb[j], acc[i][j], 0, 0, 0);
    }

    // ---- epilogue: +bias, swizzled bf16 store, per-block BN partials ----
    float s[4][4], sq[4][4];
#pragma unroll
    for (int i = 0; i < 4; ++i) {
        int cbase = wv * 64 + i * 16 + lhi * 4;
        float4 bv = *(const float4*)(bias + cbase);
        int c8 = cbase >> 3, hf = lhi & 1;
#pragma unroll
        for (int e = 0; e < 4; ++e) { s[i][e] = 0.f; sq[i][e] = 0.f; }
#pragma unroll
        for (int j = 0; j < 4; ++j) {
            int p = p0 + j * 16 + llo;
            float y0 = acc[i][j][0] + bv.x;
            float y1 = acc[i][j][1] + bv.y;
            float y2 = acc[i][j][2] + bv.z;
            float y3 = acc[i][j][3] + bv.w;
            s[i][0] += y0; sq[i][0] += y0 * y0;
            s[i][1] += y1; sq[i][1] += y1 * y1;
            s[i][2] += y2; sq[i][2] += y2 * y2;
            s[i][3] += y3; sq[i][3] += y3 * y3;
            unsigned int lo = (unsigned int)f2bf(y0) | ((unsigned int)f2bf(y1) << 16);
            unsigned int hi = (unsigned int)f2bf(y2) | ((unsigned int)f2bf(y3) << 16);
            uint2 o; o.x = lo; o.y = hi;
            *(uint2*)(Y + (size_t)p * 256 + ((c8 ^ (p & 7)) << 3) + hf * 4) = o;
        }
    }

    __syncthreads();                         // all waves done reading the tile
    float* red = (float*)smem;               // [2][16][257]
#pragma unroll
    for (int i = 0; i < 4; ++i) {
        int cbase = wv * 64 + i * 16 + lhi * 4;
#pragma unroll
        for (int e = 0; e < 4; ++e) {
            red[llo * 257 + cbase + e]            = s[i][e];
            red[16 * 257 + llo * 257 + cbase + e] = sq[i][e];
        }
    }
    __syncthreads();
    {
        float ssum = 0.f, qsum = 0.f;
#pragma unroll 4
        for (int l = 0; l < 16; ++l) {
            ssum += red[l * 257 + t];
            qsum += red[16 * 257 + l * 257 + t];
        }
        partial[(size_t)blockIdx.x * 512 + t]       = ssum;
        partial[(size_t)blockIdx.x * 512 + 256 + t] = qsum;
    }
}

// ---------------------------------------------------------------------------
// Stats reduce: 1024 block-partials -> 64 -> affine(a,c)
// ---------------------------------------------------------------------------
__global__ void k_red1(const float* __restrict__ partial, float* __restrict__ partA) {
    int t = threadIdx.x, g = blockIdx.x;
    float s = 0.f, q = 0.f;
#pragma unroll
    for (int i = 0; i < 16; ++i) {
        const float* pp = partial + (size_t)(g * 16 + i) * 512;
        s += pp[t]; q += pp[256 + t];
    }
    partA[g * 512 + t]       = s;
    partA[g * 512 + 256 + t] = q;
}

__global__ void k_finalize(const float* __restrict__ partA, const float* __restrict__ gamma,
                           const float* __restrict__ beta, float* __restrict__ aff_a,
                           float* __restrict__ aff_c) {
    int c = threadIdx.x;
    float s = 0.f, q = 0.f;
#pragma unroll 8
    for (int i = 0; i < 64; ++i) { s += partA[i * 512 + c]; q += partA[i * 512 + 256 + c]; }
    float mean = s * (1.0f / PTOT);
    float var  = fmaxf(q * (1.0f / PTOT) - mean * mean, 0.0f);
    float a    = gamma[c] / sqrtf(var + 1e-5f);
    aff_a[c] = a;
    aff_c[c] = beta[c] - mean * a;
}

// ---------------------------------------------------------------------------
// x[p][c] = sum_j w_j * kfT[b][idx_j][c] + (y0[p][c]*a0[c] + c0[c])
// y0 and X chunk-swizzled; kfT linear. 32 threads/point, 8 ch/thread.
// ---------------------------------------------------------------------------
__global__ void k_build_x(const unsigned short* __restrict__ y0, const unsigned short* __restrict__ kfT,
                          const int* __restrict__ idx, const float* __restrict__ wgt,
                          const float* __restrict__ aff_a, const float* __restrict__ aff_c,
                          unsigned short* __restrict__ X) {
    int t   = threadIdx.x;
    int p   = blockIdx.x * 8 + (t >> 5);
    int col = t & 31;               // logical chunk
    int c0  = col * 8;
    int b   = p >> 12;
    int pos = col ^ (p & 7);        // swizzled position (256-wide rows)
    int i0 = idx[p * 3 + 0], i1 = idx[p * 3 + 1], i2 = idx[p * 3 + 2];
    float w0 = wgt[p * 3 + 0], w1 = wgt[p * 3 + 1], w2 = wgt[p * 3 + 2];
    const size_t kb = (size_t)b * MPTS * C2;
    uint4 v0 = *(const uint4*)(kfT + kb + (size_t)i0 * C2 + c0);
    uint4 v1 = *(const uint4*)(kfT + kb + (size_t)i1 * C2 + c0);
    uint4 v2 = *(const uint4*)(kfT + kb + (size_t)i2 * C2 + c0);
    uint4 vy = *(const uint4*)(y0 + (size_t)p * C2 + pos * 8);
    const unsigned int* u0 = (const unsigned int*)&v0;
    const unsigned int* u1 = (const unsigned int*)&v1;
    const unsigned int* u2 = (const unsigned int*)&v2;
    const unsigned int* uy = (const unsigned int*)&vy;
    unsigned int r[4];
#pragma unroll
    for (int q = 0; q < 4; ++q) {
        int c = c0 + q * 2;
        float lo = w0 * bf2f(u0[q] & 0xffff) + w1 * bf2f(u1[q] & 0xffff) + w2 * bf2f(u2[q] & 0xffff)
                 + bf2f(uy[q] & 0xffff) * aff_a[c] + aff_c[c];
        float hi = w0 * bf2f(u0[q] >> 16) + w1 * bf2f(u1[q] >> 16) + w2 * bf2f(u2[q] >> 16)
                 + bf2f(uy[q] >> 16) * aff_a[c + 1] + aff_c[c + 1];
        r[q] = (unsigned int)f2bf(lo) | ((unsigned int)f2bf(hi) << 16);
    }
    uint4 vout; vout.x = r[0]; vout.y = r[1]; vout.z = r[2]; vout.w = r[3];
    *(uint4*)(X + (size_t)p * C2 + pos * 8) = vout;
}

// ---------------------------------------------------------------------------
// Final: out(B,256,n) f32 = relu(y2*a2+c2), from swizzled (P,256) bf16.
// ---------------------------------------------------------------------------
__global__ void k_final(const unsigned short* __restrict__ Y2, const float* __restrict__ aff_a,
                        const float* __restrict__ aff_c, float* __restrict__ out) {
    __shared__ float tile[64][65];   // [c][p]
    int p0 = blockIdx.x * 64;
    int c0 = blockIdx.y * 64;
    int t  = threadIdx.x;
    int t4 = t >> 6, t64 = t & 63;
#pragma unroll
    for (int i = 0; i < 16; ++i) {
        int r = i * 4 + t4;               // point within tile
        int p = p0 + r;
        int c = c0 + t64;
        float v = bf2f(Y2[(size_t)p * 256 + (((c >> 3) ^ (p & 7)) << 3) + (c & 7)])
                  * aff_a[c] + aff_c[c];
        tile[t64][r] = fmaxf(v, 0.0f);
    }
    __syncthreads();
    int b   = p0 >> 12;
    int pin = p0 & 4095;
#pragma unroll
    for (int i = 0; i < 16; ++i) {
        int cc = i * 4 + t4;
        out[((size_t)b * 256 + c0 + cc) * 4096 + pin + t64] = tile[cc][t64];
    }
}

// ---------------------------------------------------------------------------
extern "C" void kernel_launch(void* const* d_in, const int* in_sizes, int n_in,
                              void* d_out, int out_size, void* d_ws, size_t ws_size,
                              hipStream_t stream) {
    const float* unknown = (const float*)d_in[0];
    const float* known   = (const float*)d_in[1];
    const float* ufeat   = (const float*)d_in[2];
    const float* kfeat   = (const float*)d_in[3];
    const float* Wu      = (const float*)d_in[4];
    const float* bu      = (const float*)d_in[5];
    const float* gu      = (const float*)d_in[6];
    const float* betau   = (const float*)d_in[7];
    const float* W1      = (const float*)d_in[8];
    const float* b1      = (const float*)d_in[9];
    const float* g1      = (const float*)d_in[10];
    const float* beta1   = (const float*)d_in[11];
    const float* W2      = (const float*)d_in[12];
    const float* b2      = (const float*)d_in[13];
    const float* g2      = (const float*)d_in[14];
    const float* beta2   = (const float*)d_in[15];
    float* out = (float*)d_out;

    // workspace layout (<74 MB static + region-reused stats buffers)
    char* ws = (char*)d_ws;
    unsigned short* reg0 = (unsigned short*)ws;                        // 32MB: uT -> x -> y2
    unsigned short* ybuf = (unsigned short*)(ws + ((size_t)32 << 20)); // 32MB: y0 -> y1
    unsigned short* kfT  = (unsigned short*)(ws + ((size_t)64 << 20)); // 8MB (dead after build_x)
    unsigned short* Wub  = (unsigned short*)(ws + ((size_t)72 << 20)); // 64KB
    unsigned short* W1b  = Wub + 256 * 128;                            // 128KB
    unsigned short* W2b  = W1b + 256 * 256;                            // 128KB
    int*   idxb = (int*)(W2b + 256 * 256);                             // 768KB
    float* wgtb = (float*)(idxb + (size_t)PTOT * 3);                   // 768KB
    float* affa0 = wgtb + (size_t)PTOT * 3;
    float* affc0 = affa0 + 256;
    float* affa1 = affc0 + 256;
    float* affc1 = affa1 + 256;
    float* affa2 = affc1 + 256;
    float* affc2 = affa2 + 256;
    // stats scratch, region-reused:
    //  layer 0: lives in reg0[16MB..] (uT only occupies [0,16MB); consumed pre-build_x)
    float* part0  = (float*)(ws + ((size_t)16 << 20));                 // 2MB
    float* partA0 = (float*)(ws + ((size_t)18 << 20));                 // 128KB
    //  layers 1,2: live in the kfT region (kfT dead after build_x)
    float* part12  = (float*)(ws + ((size_t)64 << 20));                // 2MB
    float* partA12 = (float*)(ws + ((size_t)66 << 20));                // 128KB
    if (ws_size < ((size_t)75 << 20)) return;

    // 1) layout prep
    k_transpose<1><<<dim3(NPTS / 64, C1 / 64, BATCH), 256, 0, stream>>>(ufeat, reg0, C1, NPTS);
    k_transpose<0><<<dim3(MPTS / 64, C2 / 64, BATCH), 256, 0, stream>>>(kfeat, kfT, C2, MPTS);
    k_cvt<<<(256 * 128 + 255) / 256, 256, 0, stream>>>(Wu, Wub, 256 * 128);
    k_cvt<<<(256 * 256 + 255) / 256, 256, 0, stream>>>(W1, W1b, 256 * 256);
    k_cvt<<<(256 * 256 + 255) / 256, 256, 0, stream>>>(W2, W2b, 256 * 256);

    // 2) three_nn
    k_three_nn<<<PTOT / 64, 256, 0, stream>>>(unknown, known, idxb, wgtb);

    // 3) y0 = Wu @ uT + bu (stats fused)
    k_gemm<C1, 0><<<PTOT / 64, 256, 0, stream>>>(Wub, reg0, bu, nullptr, nullptr, ybuf, part0);
    k_red1<<<64, 256, 0, stream>>>(part0, partA0);
    k_finalize<<<1, 256, 0, stream>>>(partA0, gu, betau, affa0, affc0);

    // 4) x = interpolate + BN(y0)
    k_build_x<<<PTOT / 8, 256, 0, stream>>>(ybuf, kfT, idxb, wgtb, affa0, affc0, reg0);

    // 5) y1 = W1 @ x + b1 (stats fused)
    k_gemm<C2, 0><<<PTOT / 64, 256, 0, stream>>>(W1b, reg0, b1, nullptr, nullptr, ybuf, part12);
    k_red1<<<64, 256, 0, stream>>>(part12, partA12);
    k_finalize<<<1, 256, 0, stream>>>(partA12, g1, beta1, affa1, affc1);

    // 6) y2 = W2 @ relu(BN(y1)) + b2 (stats fused)
    k_gemm<C2, 1><<<PTOT / 64, 256, 0, stream>>>(W2b, ybuf, b2, affa1, affc1, reg0, part12);
    k_red1<<<64, 256, 0, stream>>>(part12, partA12);
    k_finalize<<<1, 256, 0, stream>>>(partA12, g2, beta2, affa2, affc2);

    // 7) out = relu(BN(y2)) transposed to (B, 256, n) f32
    k_final<<<dim3(PTOT / 64, 4), 256, 0, stream>>>(reg0, affa2, affc2, out);

    (void)in_sizes; (void)n_in; (void)out_size;
}

// Round 4
// 211.298 us; speedup vs baseline: 1.9538x; 1.0677x over previous
//
#include <hip/hip_runtime.h>
#include <hip/hip_bf16.h>
#include <cstddef>
#include <cstdint>

// Problem constants (from setup_inputs): B=16, n=4096, m=1024, C1=128, C2=C=256
#define BATCH 16
#define NPTS  4096
#define MPTS  1024
#define PTOT  65536      // BATCH*NPTS
#define C1    128
#define C2    256

typedef short bf16x8 __attribute__((ext_vector_type(8)));
typedef float f32x4  __attribute__((ext_vector_type(4)));

static __device__ __forceinline__ float bf2f(unsigned int u16) {
    union { unsigned int i; float f; } v; v.i = u16 << 16; return v.f;
}
static __device__ __forceinline__ unsigned short f2bf(float f) {
    union { float f; unsigned int i; } v; v.f = f;
    unsigned int u = v.i;
    return (unsigned short)((u + 0x7FFFu + ((u >> 16) & 1u)) >> 16);
}

// Swizzled activation layout: (P, C) bf16 rows; within each row the 16B
// chunks (8 channels) are stored at position chunk ^ (p & 7). Linear
// global_load_lds image of a 64-row tile then reads via swizzled
// ds_read_b128 (rule #21: both-sides-or-neither).

// ---------------------------------------------------------------------------
// Transpose (B, C, N) f32 -> (B, N, C) bf16. SWZ=1: chunk-swizzled rows.
// ---------------------------------------------------------------------------
template <int SWZ>
__global__ void k_transpose(const float* __restrict__ in, unsigned short* __restrict__ out,
                            int C, int N) {
    __shared__ float tile[64][65];
    int b  = blockIdx.z;
    int n0 = blockIdx.x * 64;
    int c0 = blockIdx.y * 64;
    const float* src = in + (size_t)b * C * N;
    unsigned short* dst = out + (size_t)b * N * C;
    int t  = threadIdx.x;
    int t4 = t >> 6;   // 0..3
    int tn = t & 63;
#pragma unroll
    for (int i = 0; i < 16; ++i) {
        int cc = i * 4 + t4;
        tile[cc][tn] = src[(size_t)(c0 + cc) * N + n0 + tn];
    }
    __syncthreads();
#pragma unroll
    for (int i = 0; i < 16; ++i) {
        int nn = i * 4 + t4;
        int p  = n0 + nn;
        int c  = c0 + tn;
        size_t off;
        if (SWZ) off = (size_t)p * C + (size_t)((((c >> 3) ^ (p & 7)) << 3) + (c & 7));
        else     off = (size_t)p * C + c;
        dst[off] = f2bf(tile[tn][nn]);
    }
}

// ---------------------------------------------------------------------------
// Weight pack: (256, K) f32 row-major -> bf16 fragment-packed
// [K/32][16 frag][64 lane][8], so a wave's MFMA A-fragment load is one
// coalesced 1KB instruction. frag id = ks*16 + wv*4 + i; lane = lhi*16+llo;
// element (ch = wv*64+i*16+llo, k = ks*32+lhi*8+e).
// ---------------------------------------------------------------------------
__global__ void k_cvt_pack(const float* __restrict__ in, unsigned short* __restrict__ out, int K) {
    int tid = blockIdx.x * 256 + threadIdx.x;
    if (tid >= 256 * K) return;
    int ch = tid / K, k = tid % K;
    int ks = k >> 5, lhi = (k >> 3) & 3, e = k & 7;
    int wv = ch >> 6, i = (ch >> 4) & 3, llo = ch & 15;
    int lane = lhi * 16 + llo;
    out[((size_t)((ks * 16 + wv * 4 + i) * 64 + lane)) * 8 + e] = f2bf(in[tid]);
}

// ---------------------------------------------------------------------------
// three_nn: 4 threads/point, chunked scan + shfl_xor butterfly merge with
// (d, idx) lexicographic comparator. Distance expr bit-exact with reference.
// ---------------------------------------------------------------------------
static __device__ __forceinline__ bool nn_less(float da, int ia, float db, int ib) {
    return (da < db) || (da == db && ia < ib);
}

__global__ void k_three_nn(const float* __restrict__ unknown, const float* __restrict__ known,
                           int* __restrict__ idx_out, float* __restrict__ w_out) {
    __shared__ float4 kpt[MPTS + 4];
    int t  = threadIdx.x;
    int p0 = blockIdx.x * 64;
    int b  = p0 >> 12;
    const float* kb = known + (size_t)b * MPTS * 3;
    for (int i = t; i < MPTS; i += 256) {
        float x = kb[i * 3 + 0], y = kb[i * 3 + 1], z = kb[i * 3 + 2];
        float dd = __fadd_rn(__fadd_rn(__fmul_rn(x, x), __fmul_rn(y, y)), __fmul_rn(z, z));
        float4 v; v.x = x; v.y = y; v.z = z; v.w = dd;
        kpt[i + (i >> 8)] = v;
    }
    __syncthreads();

    int q = t & 3;
    int p = p0 + (t >> 2);
    const float* up = unknown + (size_t)p * 3;
    float ux = up[0], uy = up[1], uz = up[2];
    float u2 = __fadd_rn(__fadd_rn(__fmul_rn(ux, ux), __fmul_rn(uy, uy)), __fmul_rn(uz, uz));

    float d0 = INFINITY, d1 = INFINITY, d2 = INFINITY;
    int   i0 = 0, i1 = 0, i2 = 0;
    int base = q * 257;
#pragma unroll 4
    for (int it = 0; it < 256; ++it) {
        float4 kp = kpt[base + it];
        float dot = __fadd_rn(__fadd_rn(__fmul_rn(ux, kp.x), __fmul_rn(uy, kp.y)),
                              __fmul_rn(uz, kp.z));
        float d = __fsub_rn(__fadd_rn(u2, kp.w), __fmul_rn(2.0f, dot));
        int k = q * 256 + it;
        if (d < d0)      { d2 = d1; i2 = i1; d1 = d0; i1 = i0; d0 = d; i0 = k; }
        else if (d < d1) { d2 = d1; i2 = i1; d1 = d;  i1 = k; }
        else if (d < d2) { d2 = d;  i2 = k; }
    }

#pragma unroll
    for (int m = 1; m <= 2; m <<= 1) {
        float e0 = __shfl_xor(d0, m, 64), e1 = __shfl_xor(d1, m, 64), e2 = __shfl_xor(d2, m, 64);
        int   j0 = __shfl_xor(i0, m, 64), j1 = __shfl_xor(i1, m, 64), j2 = __shfl_xor(i2, m, 64);
        float a0 = d0, a1 = d1, a2 = d2; int x0 = i0, x1 = i1, x2 = i2;
        float b0 = e0, b1 = e1, b2 = e2; int y0 = j0, y1 = j1, y2 = j2;
        bool tk = nn_less(a0, x0, b0, y0);
        d0 = tk ? a0 : b0; i0 = tk ? x0 : y0;
        float na0 = tk ? a1 : a0; int nx0 = tk ? x1 : x0;
        float na1 = tk ? a2 : a1; int nx1 = tk ? x2 : x1;
        float nb0 = tk ? b0 : b1; int ny0 = tk ? y0 : y1;
        float nb1 = tk ? b1 : b2; int ny1 = tk ? y1 : y2;
        tk = nn_less(na0, nx0, nb0, ny0);
        d1 = tk ? na0 : nb0; i1 = tk ? nx0 : ny0;
        float ma0 = tk ? na1 : na0; int mx0 = tk ? nx1 : nx0;
        float mb0 = tk ? nb0 : nb1; int my0 = tk ? ny0 : ny1;
        tk = nn_less(ma0, mx0, mb0, my0);
        d2 = tk ? ma0 : mb0; i2 = tk ? mx0 : my0;
    }

    if (q == 0) {
        float r0 = 1.0f / (d0 + 1e-8f), r1 = 1.0f / (d1 + 1e-8f), r2 = 1.0f / (d2 + 1e-8f);
        float norm = r0 + r1 + r2;
        size_t pg = (size_t)p;
        idx_out[pg * 3 + 0] = i0; idx_out[pg * 3 + 1] = i1; idx_out[pg * 3 + 2] = i2;
        w_out[pg * 3 + 0] = r0 / norm; w_out[pg * 3 + 1] = r1 / norm; w_out[pg * 3 + 2] = r2 / norm;
    }
}

// ---------------------------------------------------------------------------
// GEMM: Y[p][co] = sum_k W[co][k] * X[p][k] + bias[co].
// X: (PTOT, K) bf16 chunk-swizzled. Wp: fragment-packed (see k_cvt_pack).
// Y: (PTOT, 256) bf16 chunk-swizzled, stored COALESCED via LDS re-layout.
// Fused per-block BN partials via shfl reduce (each wave owns 64 channels).
// APPLY=1: x <- relu(x*aff_a + aff_c) during manual staging (GEMM3).
// ---------------------------------------------------------------------------
template <int K, int APPLY>
__global__ void k_gemm(
        const unsigned short* __restrict__ Wp,
        const unsigned short* __restrict__ X,
        const float* __restrict__ bias,
        const float* __restrict__ aff_a,
        const float* __restrict__ aff_c,
        unsigned short* __restrict__ Y,
        float* __restrict__ partial) {
    constexpr int NK = K / 32;
    constexpr int TILE_BYTES = 64 * K * 2;
    constexpr int SMEM_BYTES = TILE_BYTES > 32768 ? TILE_BYTES : 32768;
    __shared__ char smem[SMEM_BYTES];

    const int t    = threadIdx.x;
    const int p0   = blockIdx.x * 64;
    const int wv   = t >> 6;
    const int lane = t & 63;
    const int lhi  = lane >> 4, llo = lane & 15;

    // ---- stage 64 x K activation tile into LDS (swizzled image) ----
    if (!APPLY) {
        const char* src = (const char*)(X + (size_t)p0 * K);
        constexpr int ITERS = TILE_BYTES / (256 * 16);
#pragma unroll
        for (int i = 0; i < ITERS; ++i) {
            int off = (i * 256 + t) * 16;
            __builtin_amdgcn_global_load_lds(
                (const __attribute__((address_space(1))) unsigned int*)(src + off),
                (__attribute__((address_space(3))) unsigned int*)(smem + off),
                16, 0, 0);
        }
    } else {
        constexpr int CPR = K / 8;    // 16B chunks per row
#pragma unroll
        for (int i = 0; i < (64 * CPR) / 256; ++i) {
            int f   = i * 256 + t;
            int row = f / CPR, qp = f % CPR;     // qp = stored (swizzled) position
            int col = qp ^ (row & 7);            // logical chunk -> channels col*8..+7
            uint4 v = *(const uint4*)(X + (size_t)(p0 + row) * K + qp * 8);
            unsigned int w[4] = {v.x, v.y, v.z, v.w};
            float4 a0 = *(const float4*)(aff_a + col * 8);
            float4 a1 = *(const float4*)(aff_a + col * 8 + 4);
            float4 cc0 = *(const float4*)(aff_c + col * 8);
            float4 cc1 = *(const float4*)(aff_c + col * 8 + 4);
            float aa[8] = {a0.x, a0.y, a0.z, a0.w, a1.x, a1.y, a1.z, a1.w};
            float cc[8] = {cc0.x, cc0.y, cc0.z, cc0.w, cc1.x, cc1.y, cc1.z, cc1.w};
#pragma unroll
            for (int q2 = 0; q2 < 4; ++q2) {
                float lo = fmaxf(bf2f(w[q2] & 0xffff) * aa[q2 * 2]     + cc[q2 * 2],     0.0f);
                float hi = fmaxf(bf2f(w[q2] >> 16)    * aa[q2 * 2 + 1] + cc[q2 * 2 + 1], 0.0f);
                w[q2] = (unsigned int)f2bf(lo) | ((unsigned int)f2bf(hi) << 16);
            }
            uint4 o; o.x = w[0]; o.y = w[1]; o.z = w[2]; o.w = w[3];
            *(uint4*)(smem + row * (K * 2) + qp * 16) = o;
        }
    }

    // ---- weight fragments: coalesced packed loads, 2-deep ping-pong ----
    const unsigned short* wbase = Wp + ((size_t)(wv * 4 * 64) + lane) * 8;
    bf16x8 wA[4], wB[4];
#pragma unroll
    for (int i = 0; i < 4; ++i)
        wA[i] = *(const bf16x8*)(wbase + i * 512);

    __syncthreads();

    f32x4 acc[4][4];
#pragma unroll
    for (int i = 0; i < 4; ++i)
#pragma unroll
        for (int j = 0; j < 4; ++j) acc[i][j] = (f32x4){0.f, 0.f, 0.f, 0.f};

#pragma unroll
    for (int ks = 0; ks < NK; ks += 2) {
        // prefetch ks+1 fragments
#pragma unroll
        for (int i = 0; i < 4; ++i)
            wB[i] = *(const bf16x8*)(wbase + (size_t)(ks + 1) * 8192 + i * 512);
        {
            bf16x8 bb[4];
#pragma unroll
            for (int j = 0; j < 4; ++j) {
                int row = j * 16 + llo;
                int cp  = (ks * 4 + lhi) ^ (row & 7);
                bb[j] = *(const bf16x8*)(smem + row * (K * 2) + cp * 16);
            }
#pragma unroll
            for (int i = 0; i < 4; ++i)
#pragma unroll
                for (int j = 0; j < 4; ++j)
                    acc[i][j] = __builtin_amdgcn_mfma_f32_16x16x32_bf16(wA[i], bb[j], acc[i][j], 0, 0, 0);
        }
        // prefetch ks+2 fragments
        if (ks + 2 < NK) {
#pragma unroll
            for (int i = 0; i < 4; ++i)
                wA[i] = *(const bf16x8*)(wbase + (size_t)(ks + 2) * 8192 + i * 512);
        }
        {
            bf16x8 bb[4];
#pragma unroll
            for (int j = 0; j < 4; ++j) {
                int row = j * 16 + llo;
                int cp  = ((ks + 1) * 4 + lhi) ^ (row & 7);
                bb[j] = *(const bf16x8*)(smem + row * (K * 2) + cp * 16);
            }
#pragma unroll
            for (int i = 0; i < 4; ++i)
#pragma unroll
                for (int j = 0; j < 4; ++j)
                    acc[i][j] = __builtin_amdgcn_mfma_f32_16x16x32_bf16(wB[i], bb[j], acc[i][j], 0, 0, 0);
        }
    }

    // ---- epilogue: bias, bf16 image in LDS, shfl stats, coalesced store ----
    __syncthreads();                    // all waves done reading the X tile
#pragma unroll
    for (int i = 0; i < 4; ++i) {
        int cbase = wv * 64 + i * 16 + lhi * 4;
        float4 bv = *(const float4*)(bias + cbase);
        int c8 = cbase >> 3, hf = lhi & 1;
        float s0 = 0.f, s1 = 0.f, s2 = 0.f, s3 = 0.f;
        float q0 = 0.f, q1 = 0.f, q2 = 0.f, q3 = 0.f;
#pragma unroll
        for (int j = 0; j < 4; ++j) {
            int row = j * 16 + llo;
            float y0 = acc[i][j][0] + bv.x;
            float y1 = acc[i][j][1] + bv.y;
            float y2 = acc[i][j][2] + bv.z;
            float y3 = acc[i][j][3] + bv.w;
            s0 += y0; q0 += y0 * y0;  s1 += y1; q1 += y1 * y1;
            s2 += y2; q2 += y2 * y2;  s3 += y3; q3 += y3 * y3;
            unsigned int lo = (unsigned int)f2bf(y0) | ((unsigned int)f2bf(y1) << 16);
            unsigned int hi = (unsigned int)f2bf(y2) | ((unsigned int)f2bf(y3) << 16);
            uint2 o; o.x = lo; o.y = hi;
            *(uint2*)(smem + row * 512 + ((c8 ^ (row & 7)) << 4) + hf * 8) = o;
        }
#pragma unroll
        for (int m = 1; m <= 8; m <<= 1) {
            s0 += __shfl_xor(s0, m, 64); q0 += __shfl_xor(q0, m, 64);
            s1 += __shfl_xor(s1, m, 64); q1 += __shfl_xor(q1, m, 64);
            s2 += __shfl_xor(s2, m, 64); q2 += __shfl_xor(q2, m, 64);
            s3 += __shfl_xor(s3, m, 64); q3 += __shfl_xor(q3, m, 64);
        }
        if (llo == 0) {
            float4 sv; sv.x = s0; sv.y = s1; sv.z = s2; sv.w = s3;
            float4 qv; qv.x = q0; qv.y = q1; qv.z = q2; qv.w = q3;
            *(float4*)(partial + (size_t)blockIdx.x * 512 + cbase)       = sv;
            *(float4*)(partial + (size_t)blockIdx.x * 512 + 256 + cbase) = qv;
        }
    }
    __syncthreads();
    {
        const char* ysrc = smem + wv * 8192 + lane * 16;
        char* ydst = (char*)(Y + (size_t)p0 * 256) + wv * 8192 + lane * 16;
#pragma unroll
        for (int i2 = 0; i2 < 8; ++i2) {
            uint4 v = *(const uint4*)(ysrc + i2 * 1024);
            *(uint4*)(ydst + i2 * 1024) = v;
        }
    }
}

// ---------------------------------------------------------------------------
// Stats reduce: 1024 block-partials -> 64 -> affine(a,c)
// ---------------------------------------------------------------------------
__global__ void k_red1(const float* __restrict__ partial, float* __restrict__ partA) {
    int t = threadIdx.x, g = blockIdx.x;
    float s = 0.f, q = 0.f;
#pragma unroll
    for (int i = 0; i < 16; ++i) {
        const float* pp = partial + (size_t)(g * 16 + i) * 512;
        s += pp[t]; q += pp[256 + t];
    }
    partA[g * 512 + t]       = s;
    partA[g * 512 + 256 + t] = q;
}

__global__ void k_finalize(const float* __restrict__ partA, const float* __restrict__ gamma,
                           const float* __restrict__ beta, float* __restrict__ aff_a,
                           float* __restrict__ aff_c) {
    int c = threadIdx.x;
    float s = 0.f, q = 0.f;
#pragma unroll 8
    for (int i = 0; i < 64; ++i) { s += partA[i * 512 + c]; q += partA[i * 512 + 256 + c]; }
    float mean = s * (1.0f / PTOT);
    float var  = fmaxf(q * (1.0f / PTOT) - mean * mean, 0.0f);
    float a    = gamma[c] / sqrtf(var + 1e-5f);
    aff_a[c] = a;
    aff_c[c] = beta[c] - mean * a;
}

// ---------------------------------------------------------------------------
// x[p][c] = sum_j w_j * kfT[b][idx_j][c] + (y0[p][c]*a0[c] + c0[c])
// y0 and X chunk-swizzled; kfT linear. 32 threads/point, 8 ch/thread.
// ---------------------------------------------------------------------------
__global__ void k_build_x(const unsigned short* __restrict__ y0, const unsigned short* __restrict__ kfT,
                          const int* __restrict__ idx, const float* __restrict__ wgt,
                          const float* __restrict__ aff_a, const float* __restrict__ aff_c,
                          unsigned short* __restrict__ X) {
    int t   = threadIdx.x;
    int p   = blockIdx.x * 8 + (t >> 5);
    int col = t & 31;               // logical chunk
    int c0  = col * 8;
    int b   = p >> 12;
    int pos = col ^ (p & 7);        // swizzled position (256-wide rows)
    int i0 = idx[p * 3 + 0], i1 = idx[p * 3 + 1], i2 = idx[p * 3 + 2];
    float w0 = wgt[p * 3 + 0], w1 = wgt[p * 3 + 1], w2 = wgt[p * 3 + 2];
    const size_t kb = (size_t)b * MPTS * C2;
    uint4 v0 = *(const uint4*)(kfT + kb + (size_t)i0 * C2 + c0);
    uint4 v1 = *(const uint4*)(kfT + kb + (size_t)i1 * C2 + c0);
    uint4 v2 = *(const uint4*)(kfT + kb + (size_t)i2 * C2 + c0);
    uint4 vy = *(const uint4*)(y0 + (size_t)p * C2 + pos * 8);
    const unsigned int* u0 = (const unsigned int*)&v0;
    const unsigned int* u1 = (const unsigned int*)&v1;
    const unsigned int* u2 = (const unsigned int*)&v2;
    const unsigned int* uy = (const unsigned int*)&vy;
    unsigned int r[4];
#pragma unroll
    for (int q = 0; q < 4; ++q) {
        int c = c0 + q * 2;
        float lo = w0 * bf2f(u0[q] & 0xffff) + w1 * bf2f(u1[q] & 0xffff) + w2 * bf2f(u2[q] & 0xffff)
                 + bf2f(uy[q] & 0xffff) * aff_a[c] + aff_c[c];
        float hi = w0 * bf2f(u0[q] >> 16) + w1 * bf2f(u1[q] >> 16) + w2 * bf2f(u2[q] >> 16)
                 + bf2f(uy[q] >> 16) * aff_a[c + 1] + aff_c[c + 1];
        r[q] = (unsigned int)f2bf(lo) | ((unsigned int)f2bf(hi) << 16);
    }
    uint4 vout; vout.x = r[0]; vout.y = r[1]; vout.z = r[2]; vout.w = r[3];
    *(uint4*)(X + (size_t)p * C2 + pos * 8) = vout;
}

// ---------------------------------------------------------------------------
// Final: out(B,256,n) f32 = relu(y2*a2+c2), from swizzled (P,256) bf16.
// ---------------------------------------------------------------------------
__global__ void k_final(const unsigned short* __restrict__ Y2, const float* __restrict__ aff_a,
                        const float* __restrict__ aff_c, float* __restrict__ out) {
    __shared__ float tile[64][65];   // [c][p]
    int p0 = blockIdx.x * 64;
    int c0 = blockIdx.y * 64;
    int t  = threadIdx.x;
    int t4 = t >> 6, t64 = t & 63;
#pragma unroll
    for (int i = 0; i < 16; ++i) {
        int r = i * 4 + t4;               // point within tile
        int p = p0 + r;
        int c = c0 + t64;
        float v = bf2f(Y2[(size_t)p * 256 + (((c >> 3) ^ (p & 7)) << 3) + (c & 7)])
                  * aff_a[c] + aff_c[c];
        tile[t64][r] = fmaxf(v, 0.0f);
    }
    __syncthreads();
    int b   = p0 >> 12;
    int pin = p0 & 4095;
#pragma unroll
    for (int i = 0; i < 16; ++i) {
        int cc = i * 4 + t4;
        out[((size_t)b * 256 + c0 + cc) * 4096 + pin + t64] = tile[cc][t64];
    }
}

// ---------------------------------------------------------------------------
extern "C" void kernel_launch(void* const* d_in, const int* in_sizes, int n_in,
                              void* d_out, int out_size, void* d_ws, size_t ws_size,
                              hipStream_t stream) {
    const float* unknown = (const float*)d_in[0];
    const float* known   = (const float*)d_in[1];
    const float* ufeat   = (const float*)d_in[2];
    const float* kfeat   = (const float*)d_in[3];
    const float* Wu      = (const float*)d_in[4];
    const float* bu      = (const float*)d_in[5];
    const float* gu      = (const float*)d_in[6];
    const float* betau   = (const float*)d_in[7];
    const float* W1      = (const float*)d_in[8];
    const float* b1      = (const float*)d_in[9];
    const float* g1      = (const float*)d_in[10];
    const float* beta1   = (const float*)d_in[11];
    const float* W2      = (const float*)d_in[12];
    const float* b2      = (const float*)d_in[13];
    const float* g2      = (const float*)d_in[14];
    const float* beta2   = (const float*)d_in[15];
    float* out = (float*)d_out;

    // workspace layout (<74 MB static + region-reused stats buffers)
    char* ws = (char*)d_ws;
    unsigned short* reg0 = (unsigned short*)ws;                        // 32MB: uT -> x -> y2
    unsigned short* ybuf = (unsigned short*)(ws + ((size_t)32 << 20)); // 32MB: y0 -> y1
    unsigned short* kfT  = (unsigned short*)(ws + ((size_t)64 << 20)); // 8MB (dead after build_x)
    unsigned short* Wub  = (unsigned short*)(ws + ((size_t)72 << 20)); // 64KB (packed)
    unsigned short* W1b  = Wub + 256 * 128;                            // 128KB (packed)
    unsigned short* W2b  = W1b + 256 * 256;                            // 128KB (packed)
    int*   idxb = (int*)(W2b + 256 * 256);                             // 768KB
    float* wgtb = (float*)(idxb + (size_t)PTOT * 3);                   // 768KB
    float* affa0 = wgtb + (size_t)PTOT * 3;
    float* affc0 = affa0 + 256;
    float* affa1 = affc0 + 256;
    float* affc1 = affa1 + 256;
    float* affa2 = affc1 + 256;
    float* affc2 = affa2 + 256;
    // stats scratch, region-reused:
    float* part0  = (float*)(ws + ((size_t)16 << 20));                 // 2MB (inside reg0, after uT's 16MB)
    float* partA0 = (float*)(ws + ((size_t)18 << 20));                 // 128KB
    float* part12  = (float*)(ws + ((size_t)64 << 20));                // 2MB (kfT region, dead after build_x)
    float* partA12 = (float*)(ws + ((size_t)66 << 20));                // 128KB
    if (ws_size < ((size_t)75 << 20)) return;

    // 1) layout prep
    k_transpose<1><<<dim3(NPTS / 64, C1 / 64, BATCH), 256, 0, stream>>>(ufeat, reg0, C1, NPTS);
    k_transpose<0><<<dim3(MPTS / 64, C2 / 64, BATCH), 256, 0, stream>>>(kfeat, kfT, C2, MPTS);
    k_cvt_pack<<<(256 * 128 + 255) / 256, 256, 0, stream>>>(Wu, Wub, 128);
    k_cvt_pack<<<(256 * 256 + 255) / 256, 256, 0, stream>>>(W1, W1b, 256);
    k_cvt_pack<<<(256 * 256 + 255) / 256, 256, 0, stream>>>(W2, W2b, 256);

    // 2) three_nn
    k_three_nn<<<PTOT / 64, 256, 0, stream>>>(unknown, known, idxb, wgtb);

    // 3) y0 = Wu @ uT + bu (stats fused)
    k_gemm<C1, 0><<<PTOT / 64, 256, 0, stream>>>(Wub, reg0, bu, nullptr, nullptr, ybuf, part0);
    k_red1<<<64, 256, 0, stream>>>(part0, partA0);
    k_finalize<<<1, 256, 0, stream>>>(partA0, gu, betau, affa0, affc0);

    // 4) x = interpolate + BN(y0)
    k_build_x<<<PTOT / 8, 256, 0, stream>>>(ybuf, kfT, idxb, wgtb, affa0, affc0, reg0);

    // 5) y1 = W1 @ x + b1 (stats fused)
    k_gemm<C2, 0><<<PTOT / 64, 256, 0, stream>>>(W1b, reg0, b1, nullptr, nullptr, ybuf, part12);
    k_red1<<<64, 256, 0, stream>>>(part12, partA12);
    k_finalize<<<1, 256, 0, stream>>>(partA12, g1, beta1, affa1, affc1);

    // 6) y2 = W2 @ relu(BN(y1)) + b2 (stats fused)
    k_gemm<C2, 1><<<PTOT / 64, 256, 0, stream>>>(W2b, ybuf, b2, affa1, affc1, reg0, part12);
    k_red1<<<64, 256, 0, stream>>>(part12, partA12);
    k_finalize<<<1, 256, 0, stream>>>(partA12, g2, beta2, affa2, affc2);

    // 7) out = relu(BN(y2)) transposed to (B, 256, n) f32
    k_final<<<dim3(PTOT / 64, 4), 256, 0, stream>>>(reg0, affa2, affc2, out);

    (void)in_sizes; (void)n_in; (void)out_size;
}